// Round 18
// baseline (3448.223 us; speedup 1.0000x reference)
//
#include <hip/hip_runtime.h>

#define NBLK 64
#define NTHR 256
#define SEQ  512
#define BAT  64
#define NINP 256
#define NHID 512
#define LDG  2048   // 4*NHID

typedef __attribute__((ext_vector_type(8))) short short8;
typedef __attribute__((ext_vector_type(4))) float f32x4;

static __device__ __forceinline__ unsigned short f2bf(float x) {
    return __builtin_bit_cast(unsigned short, (__bf16)x);
}
static __device__ __forceinline__ float sigm(float x)  { return 1.0f / (1.0f + __expf(-x)); }
static __device__ __forceinline__ float tanh_(float x) { return 2.0f / (1.0f + __expf(-2.0f * x)) - 1.0f; }

// L3-coherent 16B load / store (bypass L1/L2), no implicit wait.
static __device__ __forceinline__ void hload(short8& d, const unsigned short* p) {
    asm volatile("global_load_dwordx4 %0, %1, off sc0 sc1" : "=v"(d) : "v"(p) : "memory");
}
static __device__ __forceinline__ void hstore16(short8 v, unsigned short* p) {
    asm volatile("global_store_dwordx4 %0, %1, off sc0 sc1" :: "v"(p), "v"(v) : "memory");
}
// plain 16B load (x prefetch), explicit issue, drained by a later counted vmcnt.
static __device__ __forceinline__ void pload(f32x4& d, const float* p) {
    asm volatile("global_load_dwordx4 %0, %1, off" : "=v"(d) : "v"(p) : "memory");
}

// d_ws: [0,16KB) per-(block,wave) flags: 256 private 64B lines (dword at (bk*4+w)*16),
//       [16KB, +2*64KB) h double buffer, block-major: [parity][block][batch][8cols] bf16.
//
// Wave-decoupled sync (4 independent all-to-alls, one per wave index).
// Counted-vmcnt schedule per step (every VMEM in the window is our own
// volatile asm; the dual-poll exits with EXACTLY ONE load in flight, and the
// destinations fA/fB are liveness-pinned until the waitcnt that retires it —
// otherwise the allocator reuses the VGPR and the landing load clobbers it):
//   vmcnt(0)                      clear deck (prev out/flag acks)
//   dual-poll flags               vmcnt(1) alternating, half-RT quantization
//   issue 16 h-loads, 16 x-loads
//   vmcnt(16); pin fA,fB          stale-poll + 16 h retired; x flying
//   hU MFMAs, gates
//   h-store
//   vmcnt(1)                      16 x retired; h-store flying
//   convert x + xW MFMAs          (true ack shadow)
//   vmcnt(0) -> flag -> out-stores
__global__ __launch_bounds__(NTHR, 1)
void lstm_persistent(const float* __restrict__ x, const float* __restrict__ W,
                     const float* __restrict__ U, const float* __restrict__ bias,
                     float* __restrict__ out, char* __restrict__ wsB)
{
    __shared__ short8 lds_s[4 * 16];   // per-wave 256B transpose staging (wave-private)

    const int bk   = blockIdx.x;
    const int tid  = threadIdx.x;
    const int w    = tid >> 6;
    const int lane = tid & 63;
    const int c16  = lane & 15;
    const int rq   = lane >> 4;

    unsigned int*   flags = (unsigned int*)wsB;
    unsigned short* hbuf  = (unsigned short*)(wsB + 16384);

    const int col0 = (c16 >> 3) * NHID + (c16 & 7) + bk * 8;   // i (c16<8) or f
    const int col1 = col0 + 2 * NHID;                           // g or o

    // ---- one-time: U,W slices into register B-fragments ----
    short8 ut[2][16];
#pragma unroll
    for (int kb = 0; kb < 16; ++kb) {
        const int k0 = kb * 32 + rq * 8;
        short8 v0, v1;
#pragma unroll
        for (int j = 0; j < 8; ++j) {
            v0[j] = (short)f2bf(U[(size_t)(k0 + j) * LDG + col0]);
            v1[j] = (short)f2bf(U[(size_t)(k0 + j) * LDG + col1]);
        }
        ut[0][kb] = v0; ut[1][kb] = v1;
    }
    short8 wt[2][8];
#pragma unroll
    for (int kb = 0; kb < 8; ++kb) {
        const int k0 = kb * 32 + rq * 8;
        short8 v0, v1;
#pragma unroll
        for (int j = 0; j < 8; ++j) {
            v0[j] = (short)f2bf(W[(size_t)(k0 + j) * LDG + col0]);
            v1[j] = (short)f2bf(W[(size_t)(k0 + j) * LDG + col1]);
        }
        wt[0][kb] = v0; wt[1][kb] = v1;
    }
    const float bias0 = bias[col0];
    const float bias1 = bias[col1];

    const int  arow  = w * 16 + c16;
    const bool lower = (c16 < 8);
    const bool up    = (c16 & 8);
    const int  hcol  = bk * 8 + (c16 & 7);
    float cst[4] = {0.f, 0.f, 0.f, 0.f};

    float* hout  = out + (size_t)SEQ * BAT * NHID;
    float* cout_ = hout + BAT * NHID;

    unsigned short* lds_w = (unsigned short*)&lds_s[w * 16];

    // ---- prologue: x(0) plain load+convert, xW(0) into accA ----
    f32x4 accA[2][4];
#pragma unroll
    for (int nt = 0; nt < 2; ++nt)
#pragma unroll
        for (int ch = 0; ch < 4; ++ch) accA[nt][ch] = (f32x4){0.f, 0.f, 0.f, 0.f};
    {
        const float* xr = x + (size_t)arow * NINP + rq * 8;
#pragma unroll
        for (int kb = 0; kb < 8; ++kb) {
            f32x4 a0 = *(const f32x4*)(xr + kb * 32);
            f32x4 a1 = *(const f32x4*)(xr + kb * 32 + 4);
            short8 v;
#pragma unroll
            for (int j = 0; j < 4; ++j) {
                v[j]     = (short)f2bf(a0[j]);
                v[j + 4] = (short)f2bf(a1[j]);
            }
            const int ch = kb & 3;
            accA[0][ch] = __builtin_amdgcn_mfma_f32_16x16x32_bf16(v, wt[0][kb], accA[0][ch], 0, 0, 0);
            accA[1][ch] = __builtin_amdgcn_mfma_f32_16x16x32_bf16(v, wt[1][kb], accA[1][ch], 0, 0, 0);
        }
    }

    f32x4 xraw[16];   // raw x(t+1): issued with the h-loads, converted in the ack shadow

    for (int t = 0; t < SEQ; ++t) {
        const int pR = (t + 1) & 1;   // parity holding h(t-1)
        const int pW = t & 1;         // parity receiving h(t)

        if (t > 0) {
            // ---- clear deck: retire prev step's out-stores + flag store ----
            asm volatile("s_waitcnt vmcnt(0)" ::: "memory");

            // ---- dual-pipelined poll of the 64 wave-w flags (lane = block) ----
            unsigned fA, fB;
            {
                const unsigned int* fp = flags + (lane * 4 + w) * 16;
                asm volatile("global_load_dword %0, %1, off sc0 sc1" : "=v"(fA) : "v"(fp) : "memory");
                for (;;) {
                    asm volatile("global_load_dword %0, %1, off sc0 sc1" : "=v"(fB) : "v"(fp) : "memory");
                    asm volatile("s_waitcnt vmcnt(1)" : "+v"(fA) :: "memory");
                    if (__all(fA >= (unsigned)t)) break;
                    asm volatile("global_load_dword %0, %1, off sc0 sc1" : "=v"(fA) : "v"(fp) : "memory");
                    asm volatile("s_waitcnt vmcnt(1)" : "+v"(fB) :: "memory");
                    if (__all(fB >= (unsigned)t)) break;
                }
                // exactly ONE poll load still in flight (its dest reg pinned below)
            }
            __builtin_amdgcn_sched_barrier(0);

            // ---- issue 16 h-loads (L3 full lines), then 16 x(t+1) loads ----
            const unsigned short* rb = hbuf + pR * 32768 + arow * 8;
            short8 hreg[16];
#pragma unroll
            for (int kb = 0; kb < 16; ++kb)
                hload(hreg[kb], rb + (kb * 4 + rq) * 512);
            if (t < SEQ - 1) {
                const float* xr = x + ((size_t)(t + 1) * BAT + arow) * NINP + rq * 8;
#pragma unroll
                for (int kb = 0; kb < 8; ++kb) {
                    pload(xraw[2 * kb],     xr + kb * 32);
                    pload(xraw[2 * kb + 1], xr + kb * 32 + 4);
                }
                // outstanding: 1 stale poll + 16 h + 16 x -> retire stale+h:
                asm volatile("s_waitcnt vmcnt(16)" ::: "memory");
            } else {
                asm volatile("s_waitcnt vmcnt(0)" ::: "memory");
            }
            // LIVENESS PIN: stale poll load has now retired; fA/fB regs were
            // reserved until here so the landing write couldn't clobber anything.
            asm volatile("" :: "v"(fA), "v"(fB));
            __builtin_amdgcn_sched_barrier(0);
#pragma unroll
            for (int kb = 0; kb < 16; ++kb) {
                const int ch = kb & 3;
                accA[0][ch] = __builtin_amdgcn_mfma_f32_16x16x32_bf16(hreg[kb], ut[0][kb], accA[0][ch], 0, 0, 0);
                accA[1][ch] = __builtin_amdgcn_mfma_f32_16x16x32_bf16(hreg[kb], ut[1][kb], accA[1][ch], 0, 0, 0);
            }
        } else {
            // t == 0: h(-1)=0, no poll/hU; just issue x(1) loads
            const float* xr = x + ((size_t)BAT + arow) * NINP + rq * 8;
#pragma unroll
            for (int kb = 0; kb < 8; ++kb) {
                pload(xraw[2 * kb],     xr + kb * 32);
                pload(xraw[2 * kb + 1], xr + kb * 32 + 4);
            }
        }

        f32x4 gif = accA[0][0] + accA[0][1] + accA[0][2] + accA[0][3];
        f32x4 ggo = accA[1][0] + accA[1][1] + accA[1][2] + accA[1][3];
#pragma unroll
        for (int j = 0; j < 4; ++j) { gif[j] += bias0; ggo[j] += bias1; }

        // ---- gate exchange + nonlinearity ----
        f32x4 oif, ogo;
#pragma unroll
        for (int j = 0; j < 4; ++j) {
            oif[j] = __shfl_xor(gif[j], 8, 64);
            ogo[j] = __shfl_xor(ggo[j], 8, 64);
        }
        float hv[4];
#pragma unroll
        for (int j = 0; j < 4; ++j) {
            const float gi = up ? oif[j] : gif[j];
            const float gf = up ? gif[j] : oif[j];
            const float gg = up ? ogo[j] : ggo[j];
            const float go = up ? ggo[j] : ogo[j];
            const float iv = sigm(gi);
            const float fv = sigm(gf);
            const float gv = tanh_(gg);
            const float ov = sigm(go);
            const float cn = fv * cst[j] + iv * gv;
            cst[j] = cn;
            hv[j] = ov * tanh_(cn);
        }

        if (t < SEQ - 1) {
            // ---- publish: LDS micro-transpose -> packed full-line h store ----
            if (lower) {
#pragma unroll
                for (int j = 0; j < 4; ++j)
                    lds_w[(rq * 4 + j) * 8 + c16] = f2bf(hv[j]);
            }
            if (lane < 16) {
                short8 hpk = lds_s[w * 16 + lane];   // same-wave LDS, compiler lgkmcnt
                hstore16(hpk, hbuf + pW * 32768 + bk * 512 + (size_t)(w * 16 + lane) * 8);
            }
            // outstanding: 16 x + 1 h-store -> retire exactly the 16 x:
            asm volatile("s_waitcnt vmcnt(1)" ::: "memory");
            __builtin_amdgcn_sched_barrier(0);
#pragma unroll
            for (int i = 0; i < 16; ++i)
                asm volatile("" : "+v"(xraw[i]));   // pin conversions after the wait

            // ---- ack shadow: zero accA, convert x(t+1), xW(t+1) MFMAs ----
#pragma unroll
            for (int nt = 0; nt < 2; ++nt)
#pragma unroll
                for (int ch = 0; ch < 4; ++ch) accA[nt][ch] = (f32x4){0.f, 0.f, 0.f, 0.f};
#pragma unroll
            for (int kb = 0; kb < 8; ++kb) {
                short8 v;
#pragma unroll
                for (int j = 0; j < 4; ++j) {
                    v[j]     = (short)f2bf(xraw[2 * kb][j]);
                    v[j + 4] = (short)f2bf(xraw[2 * kb + 1][j]);
                }
                const int ch = kb & 3;
                accA[0][ch] = __builtin_amdgcn_mfma_f32_16x16x32_bf16(v, wt[0][kb], accA[0][ch], 0, 0, 0);
                accA[1][ch] = __builtin_amdgcn_mfma_f32_16x16x32_bf16(v, wt[1][kb], accA[1][ch], 0, 0, 0);
            }
            __builtin_amdgcn_sched_barrier(0);

            // ---- retire this wave's h store; publish OWN flag (no barrier) ----
            asm volatile("s_waitcnt vmcnt(0)" ::: "memory");
            if (lane == 0) {
                unsigned int* fp2 = flags + (bk * 4 + w) * 16;   // private 64B line
                unsigned int val = (unsigned)(t + 1);
                asm volatile("global_store_dword %0, %1, off sc0 sc1"
                             :: "v"(fp2), "v"(val) : "memory");
            }

            // ---- out stores (off path; retired by next step's pre-drain) ----
            if (lower) {
#pragma unroll
                for (int j = 0; j < 4; ++j) {
                    const int batch = w * 16 + rq * 4 + j;
                    out[((size_t)t * BAT + batch) * NHID + hcol] = hv[j];
                }
            }
        } else {
            // tail step: final outputs only
            if (lower) {
#pragma unroll
                for (int j = 0; j < 4; ++j) {
                    const int batch = w * 16 + rq * 4 + j;
                    out[((size_t)t * BAT + batch) * NHID + hcol] = hv[j];
                    hout[batch * NHID + hcol]  = hv[j];
                    cout_[batch * NHID + hcol] = cst[j];
                }
            }
        }
    }
}

extern "C" void kernel_launch(void* const* d_in, const int* in_sizes, int n_in,
                              void* d_out, int out_size, void* d_ws, size_t ws_size,
                              hipStream_t stream) {
    (void)in_sizes; (void)n_in; (void)out_size; (void)ws_size;
    const float* x  = (const float*)d_in[0];
    const float* W  = (const float*)d_in[1];
    const float* U  = (const float*)d_in[2];
    const float* b  = (const float*)d_in[3];
    float* out = (float*)d_out;

    // zero per-(block,wave) flags (16KB); hbuf needs no init; replay-safe
    (void)hipMemsetAsync(d_ws, 0, 16384, stream);
    hipLaunchKernelGGL(lstm_persistent, dim3(NBLK), dim3(NTHR), 0, stream,
                       x, W, U, b, out, (char*)d_ws);
}

// Round 19
// 2485.483 us; speedup vs baseline: 1.3873x; 1.3873x over previous
//
#include <hip/hip_runtime.h>

#define NBLK 64
#define NTHR 256
#define SEQ  512
#define BAT  64
#define NINP 256
#define NHID 512
#define LDG  2048   // 4*NHID

typedef __attribute__((ext_vector_type(8))) short short8;
typedef __attribute__((ext_vector_type(4))) float f32x4;

static __device__ __forceinline__ unsigned short f2bf(float x) {
    return __builtin_bit_cast(unsigned short, (__bf16)x);
}
static __device__ __forceinline__ float sigm(float x)  { return 1.0f / (1.0f + __expf(-x)); }
static __device__ __forceinline__ float tanh_(float x) { return 2.0f / (1.0f + __expf(-2.0f * x)) - 1.0f; }

// L3-coherent 16B load / store (bypass L1/L2), no implicit wait.
static __device__ __forceinline__ void hload(short8& d, const unsigned short* p) {
    asm volatile("global_load_dwordx4 %0, %1, off sc0 sc1" : "=v"(d) : "v"(p) : "memory");
}
static __device__ __forceinline__ void hstore16(short8 v, unsigned short* p) {
    asm volatile("global_store_dwordx4 %0, %1, off sc0 sc1" :: "v"(p), "v"(v) : "memory");
}
// plain 16B load (x prefetch), explicit issue, drained by a later vmcnt(0).
static __device__ __forceinline__ void pload(f32x4& d, const float* p) {
    asm volatile("global_load_dwordx4 %0, %1, off" : "=v"(d) : "v"(p) : "memory");
}

// d_ws: [0,1KB) flags PACKED: flags[w*64 + bk] (4B stride). Wave w's 64 flags
//       are one contiguous 256B span -> 4 coalesced L3 transactions per poll
//       iteration (vs 64 scattered private lines in r16).
//       [16KB, +2*64KB) h double buffer, block-major: [parity][block][batch][8cols] bf16.
//
// Wave-decoupled sync (4 independent all-to-alls, one per wave index):
//   producer wave: h-store -> xW shadow -> vmcnt(0) -> OWN flag store  (no barrier)
//   consumer wave: poll the 64 wave-w flags (lane=block, coalesced)    (no barrier)
__global__ __launch_bounds__(NTHR, 1)
void lstm_persistent(const float* __restrict__ x, const float* __restrict__ W,
                     const float* __restrict__ U, const float* __restrict__ bias,
                     float* __restrict__ out, char* __restrict__ wsB)
{
    __shared__ short8 lds_s[4 * 16];   // per-wave 256B transpose staging (wave-private)

    const int bk   = blockIdx.x;
    const int tid  = threadIdx.x;
    const int w    = tid >> 6;
    const int lane = tid & 63;
    const int c16  = lane & 15;
    const int rq   = lane >> 4;

    unsigned int*   flags = (unsigned int*)wsB;
    unsigned short* hbuf  = (unsigned short*)(wsB + 16384);

    const int col0 = (c16 >> 3) * NHID + (c16 & 7) + bk * 8;   // i (c16<8) or f
    const int col1 = col0 + 2 * NHID;                           // g or o

    // ---- one-time: U,W slices into register B-fragments ----
    short8 ut[2][16];
#pragma unroll
    for (int kb = 0; kb < 16; ++kb) {
        const int k0 = kb * 32 + rq * 8;
        short8 v0, v1;
#pragma unroll
        for (int j = 0; j < 8; ++j) {
            v0[j] = (short)f2bf(U[(size_t)(k0 + j) * LDG + col0]);
            v1[j] = (short)f2bf(U[(size_t)(k0 + j) * LDG + col1]);
        }
        ut[0][kb] = v0; ut[1][kb] = v1;
    }
    short8 wt[2][8];
#pragma unroll
    for (int kb = 0; kb < 8; ++kb) {
        const int k0 = kb * 32 + rq * 8;
        short8 v0, v1;
#pragma unroll
        for (int j = 0; j < 8; ++j) {
            v0[j] = (short)f2bf(W[(size_t)(k0 + j) * LDG + col0]);
            v1[j] = (short)f2bf(W[(size_t)(k0 + j) * LDG + col1]);
        }
        wt[0][kb] = v0; wt[1][kb] = v1;
    }
    const float bias0 = bias[col0];
    const float bias1 = bias[col1];

    const int  arow  = w * 16 + c16;
    const bool lower = (c16 < 8);
    const bool up    = (c16 & 8);
    const int  hcol  = bk * 8 + (c16 & 7);
    float cst[4] = {0.f, 0.f, 0.f, 0.f};

    float* hout  = out + (size_t)SEQ * BAT * NHID;
    float* cout_ = hout + BAT * NHID;

    unsigned short* lds_w = (unsigned short*)&lds_s[w * 16];

    // ---- prologue: x(0) plain load+convert, xW(0) into accA ----
    f32x4 accA[2][4];
#pragma unroll
    for (int nt = 0; nt < 2; ++nt)
#pragma unroll
        for (int ch = 0; ch < 4; ++ch) accA[nt][ch] = (f32x4){0.f, 0.f, 0.f, 0.f};
    {
        const float* xr = x + (size_t)arow * NINP + rq * 8;
#pragma unroll
        for (int kb = 0; kb < 8; ++kb) {
            f32x4 a0 = *(const f32x4*)(xr + kb * 32);
            f32x4 a1 = *(const f32x4*)(xr + kb * 32 + 4);
            short8 v;
#pragma unroll
            for (int j = 0; j < 4; ++j) {
                v[j]     = (short)f2bf(a0[j]);
                v[j + 4] = (short)f2bf(a1[j]);
            }
            const int ch = kb & 3;
            accA[0][ch] = __builtin_amdgcn_mfma_f32_16x16x32_bf16(v, wt[0][kb], accA[0][ch], 0, 0, 0);
            accA[1][ch] = __builtin_amdgcn_mfma_f32_16x16x32_bf16(v, wt[1][kb], accA[1][ch], 0, 0, 0);
        }
    }

    f32x4 xraw[16];   // raw x(t+1), issued at step top, converted in the ack shadow

    for (int t = 0; t < SEQ; ++t) {
        const int pR = (t + 1) & 1;   // parity holding h(t-1)
        const int pW = t & 1;         // parity receiving h(t)

        // ---- step top: issue x(t+1) raw loads (in flight across poll + h-load) ----
        if (t < SEQ - 1) {
            const float* xr = x + ((size_t)(t + 1) * BAT + arow) * NINP + rq * 8;
#pragma unroll
            for (int kb = 0; kb < 8; ++kb) {
                pload(xraw[2 * kb],     xr + kb * 32);
                pload(xraw[2 * kb + 1], xr + kb * 32 + 4);
            }
        }

        if (t > 0) {
            // ---- detect: EVERY wave polls its 64 wave-w flags (coalesced 256B) ----
            {
                const unsigned int* fp = flags + (w * 64 + lane);
                unsigned f;
                do {
                    asm volatile("global_load_dword %0, %1, off sc0 sc1\n\t"
                                 "s_waitcnt vmcnt(0)"
                                 : "=v"(f) : "v"(fp) : "memory");
                } while (!__all(f >= (unsigned)t));
            }
            __builtin_amdgcn_sched_barrier(0);

            // ---- h @ U: 16 full-line L3 loads, ONE wait (also drains xraw) ----
            const unsigned short* rb = hbuf + pR * 32768 + arow * 8;
            short8 hreg[16];
#pragma unroll
            for (int kb = 0; kb < 16; ++kb)
                hload(hreg[kb], rb + (kb * 4 + rq) * 512);
            asm volatile("s_waitcnt vmcnt(0)" ::: "memory");
            __builtin_amdgcn_sched_barrier(0);
#pragma unroll
            for (int kb = 0; kb < 16; ++kb) {
                const int ch = kb & 3;
                accA[0][ch] = __builtin_amdgcn_mfma_f32_16x16x32_bf16(hreg[kb], ut[0][kb], accA[0][ch], 0, 0, 0);
                accA[1][ch] = __builtin_amdgcn_mfma_f32_16x16x32_bf16(hreg[kb], ut[1][kb], accA[1][ch], 0, 0, 0);
            }
        }
        // t == 0: h(-1)=0, hU skipped; accA holds xW(0) from prologue.

        f32x4 gif = accA[0][0] + accA[0][1] + accA[0][2] + accA[0][3];
        f32x4 ggo = accA[1][0] + accA[1][1] + accA[1][2] + accA[1][3];
#pragma unroll
        for (int j = 0; j < 4; ++j) { gif[j] += bias0; ggo[j] += bias1; }

        // ---- gate exchange + nonlinearity ----
        f32x4 oif, ogo;
#pragma unroll
        for (int j = 0; j < 4; ++j) {
            oif[j] = __shfl_xor(gif[j], 8, 64);
            ogo[j] = __shfl_xor(ggo[j], 8, 64);
        }
        float hv[4];
#pragma unroll
        for (int j = 0; j < 4; ++j) {
            const float gi = up ? oif[j] : gif[j];
            const float gf = up ? gif[j] : oif[j];
            const float gg = up ? ogo[j] : ggo[j];
            const float go = up ? ggo[j] : ogo[j];
            const float iv = sigm(gi);
            const float fv = sigm(gf);
            const float gv = tanh_(gg);
            const float ov = sigm(go);
            const float cn = fv * cst[j] + iv * gv;
            cst[j] = cn;
            hv[j] = ov * tanh_(cn);
        }

        if (t < SEQ - 1) {
            // ---- publish: LDS micro-transpose -> packed full-line h store ----
            if (lower) {
#pragma unroll
                for (int j = 0; j < 4; ++j)
                    lds_w[(rq * 4 + j) * 8 + c16] = f2bf(hv[j]);
            }
            if (lane < 16) {
                short8 hpk = lds_s[w * 16 + lane];   // same-wave LDS, compiler lgkmcnt
                hstore16(hpk, hbuf + pW * 32768 + bk * 512 + (size_t)(w * 16 + lane) * 8);
            }
            __builtin_amdgcn_sched_barrier(0);

            // ---- t==0: nothing has drained the xraw loads yet ----
            if (t == 0) {
                asm volatile("s_waitcnt vmcnt(0)" ::: "memory");
            }
            __builtin_amdgcn_sched_barrier(0);
            // volatile pass-through pins conversions after the preceding waitcnt
#pragma unroll
            for (int i = 0; i < 16; ++i)
                asm volatile("" : "+v"(xraw[i]));

            // ---- ack shadow: zero accA, convert x(t+1), xW(t+1) MFMAs ----
#pragma unroll
            for (int nt = 0; nt < 2; ++nt)
#pragma unroll
                for (int ch = 0; ch < 4; ++ch) accA[nt][ch] = (f32x4){0.f, 0.f, 0.f, 0.f};
#pragma unroll
            for (int kb = 0; kb < 8; ++kb) {
                short8 v;
#pragma unroll
                for (int j = 0; j < 4; ++j) {
                    v[j]     = (short)f2bf(xraw[2 * kb][j]);
                    v[j + 4] = (short)f2bf(xraw[2 * kb + 1][j]);
                }
                const int ch = kb & 3;
                accA[0][ch] = __builtin_amdgcn_mfma_f32_16x16x32_bf16(v, wt[0][kb], accA[0][ch], 0, 0, 0);
                accA[1][ch] = __builtin_amdgcn_mfma_f32_16x16x32_bf16(v, wt[1][kb], accA[1][ch], 0, 0, 0);
            }
            __builtin_amdgcn_sched_barrier(0);

            // ---- retire this wave's h store; publish OWN flag (no barrier) ----
            asm volatile("s_waitcnt vmcnt(0)" ::: "memory");
            if (lane == 0) {
                unsigned int* fp2 = flags + (w * 64 + bk);   // packed 4B slot
                unsigned int val = (unsigned)(t + 1);
                asm volatile("global_store_dword %0, %1, off sc0 sc1"
                             :: "v"(fp2), "v"(val) : "memory");
            }

            // ---- out stores (off path; drain under next step's poll) ----
            if (lower) {
#pragma unroll
                for (int j = 0; j < 4; ++j) {
                    const int batch = w * 16 + rq * 4 + j;
                    out[((size_t)t * BAT + batch) * NHID + hcol] = hv[j];
                }
            }
        } else {
            // tail step: final outputs only
            if (lower) {
#pragma unroll
                for (int j = 0; j < 4; ++j) {
                    const int batch = w * 16 + rq * 4 + j;
                    out[((size_t)t * BAT + batch) * NHID + hcol] = hv[j];
                    hout[batch * NHID + hcol]  = hv[j];
                    cout_[batch * NHID + hcol] = cst[j];
                }
            }
        }
    }
}

extern "C" void kernel_launch(void* const* d_in, const int* in_sizes, int n_in,
                              void* d_out, int out_size, void* d_ws, size_t ws_size,
                              hipStream_t stream) {
    (void)in_sizes; (void)n_in; (void)out_size; (void)ws_size;
    const float* x  = (const float*)d_in[0];
    const float* W  = (const float*)d_in[1];
    const float* U  = (const float*)d_in[2];
    const float* b  = (const float*)d_in[3];
    float* out = (float*)d_out;

    // zero packed flags (1KB; clear 4KB for safety); hbuf needs no init; replay-safe
    (void)hipMemsetAsync(d_ws, 0, 4096, stream);
    hipLaunchKernelGGL(lstm_persistent, dim3(NBLK), dim3(NTHR), 0, stream,
                       x, W, U, b, out, (char*)d_ws);
}

// Round 20
// 2238.237 us; speedup vs baseline: 1.5406x; 1.1105x over previous
//
#include <hip/hip_runtime.h>

#define NBLK 64
#define NTHR 256
#define SEQ  512
#define BAT  64
#define NINP 256
#define NHID 512
#define LDG  2048   // 4*NHID

typedef __attribute__((ext_vector_type(8))) short short8;
typedef __attribute__((ext_vector_type(4))) float f32x4;

static __device__ __forceinline__ unsigned short f2bf(float x) {
    return __builtin_bit_cast(unsigned short, (__bf16)x);
}
static __device__ __forceinline__ float sigm(float x)  { return 1.0f / (1.0f + __expf(-x)); }
static __device__ __forceinline__ float tanh_(float x) { return 2.0f / (1.0f + __expf(-2.0f * x)) - 1.0f; }

// L3-coherent 16B load / store (bypass L1/L2), no implicit wait.
static __device__ __forceinline__ void hload(short8& d, const unsigned short* p) {
    asm volatile("global_load_dwordx4 %0, %1, off sc0 sc1" : "=v"(d) : "v"(p) : "memory");
}
static __device__ __forceinline__ void hstore16(short8 v, unsigned short* p) {
    asm volatile("global_store_dwordx4 %0, %1, off sc0 sc1" :: "v"(p), "v"(v) : "memory");
}
// plain 16B load (x prefetch), explicit issue, drained by a later vmcnt(0).
static __device__ __forceinline__ void pload(f32x4& d, const float* p) {
    asm volatile("global_load_dwordx4 %0, %1, off" : "=v"(d) : "v"(p) : "memory");
}

// d_ws: [0,16KB) per-(block,wave) flags: 256 private 64B lines (dword at (bk*4+w)*16),
//       [16KB, +2*64KB) h double buffer, block-major: [parity][block][batch][8cols] bf16.
//
// WAVE-DECOUPLED sync: wave w of block b writes batch rows [16w,16w+16) and its
// readers are exactly wave w of every block. So sync is 4 independent all-to-alls:
//   producer wave: h-store -> xW shadow -> vmcnt(0) -> OWN flag store  (no barrier)
//   consumer wave: poll the 64 wave-w flags (lane=block)               (no barrier)
// This configuration (r16) measured 2230us = best of 19 rounds; r7/r8 (data-embedded
// tags), r9/r10 (XCD-local), r12 (collector), r18 (counted vmcnt), r19 (packed flags)
// all measured worse. Remaining cost is coherence-fabric latency on the serial chain.
__global__ __launch_bounds__(NTHR, 1)
void lstm_persistent(const float* __restrict__ x, const float* __restrict__ W,
                     const float* __restrict__ U, const float* __restrict__ bias,
                     float* __restrict__ out, char* __restrict__ wsB)
{
    __shared__ short8 lds_s[4 * 16];   // per-wave 256B transpose staging (wave-private)

    const int bk   = blockIdx.x;
    const int tid  = threadIdx.x;
    const int w    = tid >> 6;
    const int lane = tid & 63;
    const int c16  = lane & 15;
    const int rq   = lane >> 4;

    unsigned int*   flags = (unsigned int*)wsB;
    unsigned short* hbuf  = (unsigned short*)(wsB + 16384);

    const int col0 = (c16 >> 3) * NHID + (c16 & 7) + bk * 8;   // i (c16<8) or f
    const int col1 = col0 + 2 * NHID;                           // g or o

    // ---- one-time: U,W slices into register B-fragments ----
    short8 ut[2][16];
#pragma unroll
    for (int kb = 0; kb < 16; ++kb) {
        const int k0 = kb * 32 + rq * 8;
        short8 v0, v1;
#pragma unroll
        for (int j = 0; j < 8; ++j) {
            v0[j] = (short)f2bf(U[(size_t)(k0 + j) * LDG + col0]);
            v1[j] = (short)f2bf(U[(size_t)(k0 + j) * LDG + col1]);
        }
        ut[0][kb] = v0; ut[1][kb] = v1;
    }
    short8 wt[2][8];
#pragma unroll
    for (int kb = 0; kb < 8; ++kb) {
        const int k0 = kb * 32 + rq * 8;
        short8 v0, v1;
#pragma unroll
        for (int j = 0; j < 8; ++j) {
            v0[j] = (short)f2bf(W[(size_t)(k0 + j) * LDG + col0]);
            v1[j] = (short)f2bf(W[(size_t)(k0 + j) * LDG + col1]);
        }
        wt[0][kb] = v0; wt[1][kb] = v1;
    }
    const float bias0 = bias[col0];
    const float bias1 = bias[col1];

    const int  arow  = w * 16 + c16;
    const bool lower = (c16 < 8);
    const bool up    = (c16 & 8);
    const int  hcol  = bk * 8 + (c16 & 7);
    float cst[4] = {0.f, 0.f, 0.f, 0.f};

    float* hout  = out + (size_t)SEQ * BAT * NHID;
    float* cout_ = hout + BAT * NHID;

    unsigned short* lds_w = (unsigned short*)&lds_s[w * 16];

    // ---- prologue: x(0) load+convert, xW(0) into accA ----
    f32x4 accA[2][4];
#pragma unroll
    for (int nt = 0; nt < 2; ++nt)
#pragma unroll
        for (int ch = 0; ch < 4; ++ch) accA[nt][ch] = (f32x4){0.f, 0.f, 0.f, 0.f};
    {
        const float* xr = x + (size_t)arow * NINP + rq * 8;
#pragma unroll
        for (int kb = 0; kb < 8; ++kb) {
            f32x4 a0 = *(const f32x4*)(xr + kb * 32);
            f32x4 a1 = *(const f32x4*)(xr + kb * 32 + 4);
            short8 v;
#pragma unroll
            for (int j = 0; j < 4; ++j) {
                v[j]     = (short)f2bf(a0[j]);
                v[j + 4] = (short)f2bf(a1[j]);
            }
            const int ch = kb & 3;
            accA[0][ch] = __builtin_amdgcn_mfma_f32_16x16x32_bf16(v, wt[0][kb], accA[0][ch], 0, 0, 0);
            accA[1][ch] = __builtin_amdgcn_mfma_f32_16x16x32_bf16(v, wt[1][kb], accA[1][ch], 0, 0, 0);
        }
    }

    f32x4 xraw[16];   // raw x(t+1), issued at step top, converted in the ack shadow

    for (int t = 0; t < SEQ; ++t) {
        const int pR = (t + 1) & 1;   // parity holding h(t-1)
        const int pW = t & 1;         // parity receiving h(t)

        // ---- step top: issue x(t+1) raw loads (in flight across poll + h-load) ----
        if (t < SEQ - 1) {
            const float* xr = x + ((size_t)(t + 1) * BAT + arow) * NINP + rq * 8;
#pragma unroll
            for (int kb = 0; kb < 8; ++kb) {
                pload(xraw[2 * kb],     xr + kb * 32);
                pload(xraw[2 * kb + 1], xr + kb * 32 + 4);
            }
        }

        if (t > 0) {
            // ---- detect: EVERY wave polls the 64 wave-w flags (lane = block) ----
            {
                const unsigned int* fp = flags + (lane * 4 + w) * 16;
                unsigned f;
                do {
                    asm volatile("global_load_dword %0, %1, off sc0 sc1\n\t"
                                 "s_waitcnt vmcnt(0)"
                                 : "=v"(f) : "v"(fp) : "memory");
                } while (!__all(f >= (unsigned)t));
            }
            __builtin_amdgcn_sched_barrier(0);

            // ---- h @ U: 16 full-line L3 loads, ONE wait (also drains xraw) ----
            const unsigned short* rb = hbuf + pR * 32768 + arow * 8;
            short8 hreg[16];
#pragma unroll
            for (int kb = 0; kb < 16; ++kb)
                hload(hreg[kb], rb + (kb * 4 + rq) * 512);
            asm volatile("s_waitcnt vmcnt(0)" ::: "memory");
            __builtin_amdgcn_sched_barrier(0);
#pragma unroll
            for (int kb = 0; kb < 16; ++kb) {
                const int ch = kb & 3;
                accA[0][ch] = __builtin_amdgcn_mfma_f32_16x16x32_bf16(hreg[kb], ut[0][kb], accA[0][ch], 0, 0, 0);
                accA[1][ch] = __builtin_amdgcn_mfma_f32_16x16x32_bf16(hreg[kb], ut[1][kb], accA[1][ch], 0, 0, 0);
            }
        }
        // t == 0: h(-1)=0, hU skipped; accA holds xW(0) from prologue.

        f32x4 gif = accA[0][0] + accA[0][1] + accA[0][2] + accA[0][3];
        f32x4 ggo = accA[1][0] + accA[1][1] + accA[1][2] + accA[1][3];
#pragma unroll
        for (int j = 0; j < 4; ++j) { gif[j] += bias0; ggo[j] += bias1; }

        // ---- gate exchange + nonlinearity ----
        f32x4 oif, ogo;
#pragma unroll
        for (int j = 0; j < 4; ++j) {
            oif[j] = __shfl_xor(gif[j], 8, 64);
            ogo[j] = __shfl_xor(ggo[j], 8, 64);
        }
        float hv[4];
#pragma unroll
        for (int j = 0; j < 4; ++j) {
            const float gi = up ? oif[j] : gif[j];
            const float gf = up ? gif[j] : oif[j];
            const float gg = up ? ogo[j] : ggo[j];
            const float go = up ? ggo[j] : ogo[j];
            const float iv = sigm(gi);
            const float fv = sigm(gf);
            const float gv = tanh_(gg);
            const float ov = sigm(go);
            const float cn = fv * cst[j] + iv * gv;
            cst[j] = cn;
            hv[j] = ov * tanh_(cn);
        }

        if (t < SEQ - 1) {
            // ---- publish: LDS micro-transpose -> packed full-line h store ----
            if (lower) {
#pragma unroll
                for (int j = 0; j < 4; ++j)
                    lds_w[(rq * 4 + j) * 8 + c16] = f2bf(hv[j]);
            }
            if (lane < 16) {
                short8 hpk = lds_s[w * 16 + lane];   // same-wave LDS, compiler lgkmcnt
                hstore16(hpk, hbuf + pW * 32768 + bk * 512 + (size_t)(w * 16 + lane) * 8);
            }
            __builtin_amdgcn_sched_barrier(0);

            // ---- t==0: nothing has drained the xraw loads yet ----
            if (t == 0) {
                asm volatile("s_waitcnt vmcnt(0)" ::: "memory");
            }
            __builtin_amdgcn_sched_barrier(0);
            // volatile pass-through pins conversions after the preceding waitcnt
#pragma unroll
            for (int i = 0; i < 16; ++i)
                asm volatile("" : "+v"(xraw[i]));

            // ---- ack shadow: zero accA, convert x(t+1), xW(t+1) MFMAs ----
#pragma unroll
            for (int nt = 0; nt < 2; ++nt)
#pragma unroll
                for (int ch = 0; ch < 4; ++ch) accA[nt][ch] = (f32x4){0.f, 0.f, 0.f, 0.f};
#pragma unroll
            for (int kb = 0; kb < 8; ++kb) {
                short8 v;
#pragma unroll
                for (int j = 0; j < 4; ++j) {
                    v[j]     = (short)f2bf(xraw[2 * kb][j]);
                    v[j + 4] = (short)f2bf(xraw[2 * kb + 1][j]);
                }
                const int ch = kb & 3;
                accA[0][ch] = __builtin_amdgcn_mfma_f32_16x16x32_bf16(v, wt[0][kb], accA[0][ch], 0, 0, 0);
                accA[1][ch] = __builtin_amdgcn_mfma_f32_16x16x32_bf16(v, wt[1][kb], accA[1][ch], 0, 0, 0);
            }
            __builtin_amdgcn_sched_barrier(0);

            // ---- retire this wave's h store; publish OWN flag (no barrier) ----
            asm volatile("s_waitcnt vmcnt(0)" ::: "memory");
            if (lane == 0) {
                unsigned int* fp2 = flags + (bk * 4 + w) * 16;   // private 64B line
                unsigned int val = (unsigned)(t + 1);
                asm volatile("global_store_dword %0, %1, off sc0 sc1"
                             :: "v"(fp2), "v"(val) : "memory");
            }

            // ---- out stores (off path; drain under next step's poll) ----
            if (lower) {
#pragma unroll
                for (int j = 0; j < 4; ++j) {
                    const int batch = w * 16 + rq * 4 + j;
                    out[((size_t)t * BAT + batch) * NHID + hcol] = hv[j];
                }
            }
        } else {
            // tail step: final outputs only
            if (lower) {
#pragma unroll
                for (int j = 0; j < 4; ++j) {
                    const int batch = w * 16 + rq * 4 + j;
                    out[((size_t)t * BAT + batch) * NHID + hcol] = hv[j];
                    hout[batch * NHID + hcol]  = hv[j];
                    cout_[batch * NHID + hcol] = cst[j];
                }
            }
        }
    }
}

extern "C" void kernel_launch(void* const* d_in, const int* in_sizes, int n_in,
                              void* d_out, int out_size, void* d_ws, size_t ws_size,
                              hipStream_t stream) {
    (void)in_sizes; (void)n_in; (void)out_size; (void)ws_size;
    const float* x  = (const float*)d_in[0];
    const float* W  = (const float*)d_in[1];
    const float* U  = (const float*)d_in[2];
    const float* b  = (const float*)d_in[3];
    float* out = (float*)d_out;

    // zero per-(block,wave) flags (16KB); hbuf needs no init; replay-safe
    (void)hipMemsetAsync(d_ws, 0, 16384, stream);
    hipLaunchKernelGGL(lstm_persistent, dim3(NBLK), dim3(NTHR), 0, stream,
                       x, W, U, b, out, (char*)d_ws);
}